// Round 2
// baseline (9449.644 us; speedup 1.0000x reference)
//
#include <hip/hip_runtime.h>
#include <hip/hip_bf16.h>
#include <math.h>

#define RSQ 0.99999500003749969f   // 1/sqrt(1+1e-5)
#define SLOPE 0.01f

__device__ __forceinline__ float sigmoidf_(float x){ return 1.0f/(1.0f+expf(-x)); }

// ---------------- mask: prod_k cos(fW*rng + fB) ----------------
__global__ void mask_partial_kernel(const float* __restrict__ fW, const float* __restrict__ fB,
                                    float* __restrict__ partial)
{
    int p = blockIdx.x*256 + threadIdx.x;   // 0..15902 (31*513)
    if (p >= 15903) return;
    int w = p % 513;
    float r = (float)(w + 1);
    int k0 = blockIdx.y * 32;
    float prod = 1.0f;
    for (int k = k0; k < k0 + 32; ++k) {
        float a = fW[(size_t)k*15903 + p] * r + fB[(size_t)k*15903 + p];
        prod *= cosf(a);
    }
    partial[blockIdx.y*15903 + p] = prod;
}

__global__ void mask_finalize_apply(const float* __restrict__ partial, const float* __restrict__ x,
                                    float* __restrict__ xm)
{
    int p = blockIdx.x*256 + threadIdx.x;
    if (p >= 15903) return;
    float m = 1.0f;
    #pragma unroll
    for (int c = 0; c < 32; ++c) m *= partial[c*15903 + p];
    for (int n = 0; n < 32; ++n)
        xm[(size_t)n*15903 + p] = x[(size_t)n*15903 + p] * m;
}

// ---------------- 3x3 SAME conv (+optional bn+lrelu), chunked over batch ----------------
// grid: (ceil(H*ceil(W/2)/256), Cout/4, NC); thread: 4 co x 2 w
__launch_bounds__(256)
__global__ void conv3x3_kernel(const float* __restrict__ in, const float* __restrict__ wgt,
                               float* __restrict__ out,
                               int Cin, int Cout, int H, int W,
                               const float* __restrict__ bng, const float* __restrict__ bnb, int act)
{
    __shared__ float wl[4*256*9];           // max Cin = 256 -> 36 KB
    const int Wp = (W + 1) >> 1;
    const int cog = blockIdx.y;
    const int n = blockIdx.z;

    {
        int nw = 4*Cin*9;
        const float* wsrc = wgt + (size_t)cog*nw;
        for (int i = threadIdx.x; i < nw; i += 256) wl[i] = wsrc[i];
    }
    __syncthreads();

    int id = blockIdx.x*256 + threadIdx.x;
    int w0 = (id % Wp) * 2;
    int h  = id / Wp;
    if (h >= H) return;

    float acc[4][2] = {};
    const float* inb = in + (size_t)n*Cin*H*W;

    for (int ci = 0; ci < Cin; ++ci) {
        float win[3][4];
        const float* ip = inb + (size_t)ci*H*W;
        #pragma unroll
        for (int dh = 0; dh < 3; ++dh) {
            int hh = h - 1 + dh;
            bool hv = (unsigned)hh < (unsigned)H;
            #pragma unroll
            for (int dw = 0; dw < 4; ++dw) {
                int ww = w0 - 1 + dw;
                bool v = hv && ((unsigned)ww < (unsigned)W);
                win[dh][dw] = v ? ip[(size_t)hh*W + ww] : 0.0f;
            }
        }
        #pragma unroll
        for (int c = 0; c < 4; ++c) {
            const float* wr = &wl[(c*Cin + ci)*9];
            #pragma unroll
            for (int kh = 0; kh < 3; ++kh) {
                #pragma unroll
                for (int kw = 0; kw < 3; ++kw) {
                    float wv = wr[kh*3 + kw];
                    acc[c][0] += win[kh][kw]   * wv;
                    acc[c][1] += win[kh][kw+1] * wv;
                }
            }
        }
    }

    #pragma unroll
    for (int c = 0; c < 4; ++c) {
        int co = cog*4 + c;
        float v0 = acc[c][0], v1 = acc[c][1];
        if (bng) {
            float s = bng[co] * RSQ;
            float bb = bnb[co];
            v0 = v0*s + bb; v1 = v1*s + bb;
        }
        if (act) {
            v0 = (v0 >= 0.f) ? v0 : SLOPE*v0;
            v1 = (v1 >= 0.f) ? v1 : SLOPE*v1;
        }
        float* op = out + (((size_t)n*Cout + co)*H + h)*W + w0;
        op[0] = v0;
        if (w0 + 1 < W) op[1] = v1;
    }
}

// ---- 3x3 conv (+optional 1x1 shortcut) + bn + lrelu + maxpool(1,4) fused ----
// grid: (ceil(H*Wout/256), Cout/4, NC); thread: 4 co x 1 pooled output
__launch_bounds__(256)
__global__ void conv3x3_scpool_kernel(const float* __restrict__ in, const float* __restrict__ wgt,
                                      const float* __restrict__ xin, const float* __restrict__ swgt,
                                      float* __restrict__ out,
                                      int Cin, int Cs, int Cout, int H, int W, int Wout,
                                      const float* __restrict__ g, const float* __restrict__ b)
{
    __shared__ float wl[4*256*9];   // 36 KB
    __shared__ float swl[4*192];    // 3 KB
    const int cog = blockIdx.y;
    const int n = blockIdx.z;

    {
        int nw = 4*Cin*9;
        const float* wsrc = wgt + (size_t)cog*nw;
        for (int i = threadIdx.x; i < nw; i += 256) wl[i] = wsrc[i];
        if (swgt) {
            const float* ss = swgt + (size_t)cog*4*Cs;
            for (int i = threadIdx.x; i < 4*Cs; i += 256) swl[i] = ss[i];
        }
    }
    __syncthreads();

    int id = blockIdx.x*256 + threadIdx.x;
    int wo = id % Wout;
    int h  = id / Wout;
    if (h >= H) return;
    int wbase = wo*4;

    float acc[4][4] = {};
    const float* inb = in + (size_t)n*Cin*H*W;

    for (int ci = 0; ci < Cin; ++ci) {
        const float* ip = inb + (size_t)ci*H*W;
        float win[3][6];
        #pragma unroll
        for (int dh = 0; dh < 3; ++dh) {
            int hh = h - 1 + dh;
            bool hv = (unsigned)hh < (unsigned)H;
            #pragma unroll
            for (int dw = 0; dw < 6; ++dw) {
                int ww = wbase - 1 + dw;
                bool v = hv && ((unsigned)ww < (unsigned)W);
                win[dh][dw] = v ? ip[(size_t)hh*W + ww] : 0.0f;
            }
        }
        #pragma unroll
        for (int c = 0; c < 4; ++c) {
            const float* wr = &wl[(c*Cin + ci)*9];
            #pragma unroll
            for (int kh = 0; kh < 3; ++kh) {
                #pragma unroll
                for (int kw = 0; kw < 3; ++kw) {
                    float wv = wr[kh*3 + kw];
                    #pragma unroll
                    for (int p = 0; p < 4; ++p)
                        acc[c][p] += win[kh][kw + p] * wv;
                }
            }
        }
    }

    if (swgt) {
        const float* xb = xin + (size_t)n*Cs*H*W;
        for (int ci = 0; ci < Cs; ++ci) {
            const float* xp_ = xb + ((size_t)ci*H + h)*W + wbase;
            float x0 = xp_[0], x1 = xp_[1], x2 = xp_[2], x3 = xp_[3];
            #pragma unroll
            for (int c = 0; c < 4; ++c) {
                float sv = swl[c*Cs + ci];
                acc[c][0] += x0*sv; acc[c][1] += x1*sv;
                acc[c][2] += x2*sv; acc[c][3] += x3*sv;
            }
        }
    }

    #pragma unroll
    for (int c = 0; c < 4; ++c) {
        int co = cog*4 + c;
        float s = g[co]*RSQ, bo = b[co];
        float m = -1e30f;
        #pragma unroll
        for (int p = 0; p < 4; ++p) {
            float v = acc[c][p]*s + bo;
            v = (v >= 0.f) ? v : SLOPE*v;
            m = fmaxf(m, v);
        }
        out[(((size_t)n*Cout + co)*H + h)*Wout + wo] = m;
    }
}

// ---------------- feats: (32,256,31,2) -> (32,31,512) ----------------
__global__ void feats_kernel(const float* __restrict__ p4, float* __restrict__ feats)
{
    int idx = blockIdx.x*256 + threadIdx.x;   // total 507904
    int cw = idx % 512;
    int h  = (idx / 512) % 31;
    int n  = idx / (512*31);
    int c = cw >> 1, w = cw & 1;
    feats[idx] = p4[(((size_t)n*256 + c)*31 + h)*2 + w];
}

// ---------------- whh (1024,256) -> whhT (256,1024) ----------------
__global__ void transpose_whh_kernel(const float* __restrict__ whh, float* __restrict__ whhT)
{
    int idx = blockIdx.x*256 + threadIdx.x;  // 262144 exact
    int j = idx >> 8, k = idx & 255;
    whhT[(size_t)k*1024 + j] = whh[idx];
}

// ---------------- tiled SGEMM: C[M,N] = A[M,K] @ B[N,K]^T + bias(+bias2) ----------------
#define GM 32
#define GN 64
#define GK 32
__launch_bounds__(256)
__global__ void gemm_bias_kernel(const float* __restrict__ A, const float* __restrict__ B,
                                 const float* __restrict__ bias, const float* __restrict__ bias2,
                                 float* __restrict__ C, int M, int N, int K)
{
    __shared__ float As[GM][GK+1];
    __shared__ float Bs[GN][GK+1];
    int m0 = blockIdx.x*GM, n0 = blockIdx.y*GN;
    int tid = threadIdx.x;
    int mi = tid >> 4;
    int ni = (tid & 15) * 4;
    float acc[2][4] = {};

    for (int k0 = 0; k0 < K; k0 += GK) {
        for (int i = tid; i < GM*GK; i += 256) {
            int r = i >> 5, c = i & 31;
            int m = m0 + r;
            As[r][c] = (m < M) ? A[(size_t)m*K + k0 + c] : 0.f;
        }
        for (int i = tid; i < GN*GK; i += 256) {
            int r = i >> 5, c = i & 31;
            int n = n0 + r;
            Bs[r][c] = (n < N) ? B[(size_t)n*K + k0 + c] : 0.f;
        }
        __syncthreads();
        #pragma unroll
        for (int kk = 0; kk < GK; ++kk) {
            float a0 = As[mi][kk], a1 = As[mi+16][kk];
            float b0 = Bs[ni][kk], b1 = Bs[ni+1][kk], b2 = Bs[ni+2][kk], b3 = Bs[ni+3][kk];
            acc[0][0] += a0*b0; acc[0][1] += a0*b1; acc[0][2] += a0*b2; acc[0][3] += a0*b3;
            acc[1][0] += a1*b0; acc[1][1] += a1*b1; acc[1][2] += a1*b2; acc[1][3] += a1*b3;
        }
        __syncthreads();
    }
    #pragma unroll
    for (int r = 0; r < 2; ++r) {
        int m = m0 + mi + r*16;
        if (m >= M) continue;
        #pragma unroll
        for (int q = 0; q < 4; ++q) {
            int n = n0 + ni + q;
            if (n >= N) continue;
            float v = acc[r][q];
            if (bias)  v += bias[n];
            if (bias2) v += bias2[n];
            C[(size_t)m*N + n] = v;
        }
    }
}

// ---------------- LSTM scan (one direction): 32 blocks = batch ----------------
// xp: [b][t][1024] (input projection incl. both biases); whhT: [k=256][j=1024]
// hcat: [b][t][512]; dir d -> cols d*256..d*256+255
__launch_bounds__(256)
__global__ void lstm_scan_kernel(const float* __restrict__ xp, const float* __restrict__ whhT,
                                 float* __restrict__ hcat, int d)
{
    int b = blockIdx.x;
    int tid = threadIdx.x;

    __shared__ float hs[256];
    __shared__ float gl[1024];
    hs[tid] = 0.f;
    float c = 0.f;
    __syncthreads();

    for (int step = 0; step < 31; ++step) {
        int t = d ? (30 - step) : step;
        const float* x = xp + ((size_t)b*31 + t)*1024;
        float4 xg = *(const float4*)(x + (tid << 2));
        float g0 = xg.x, g1 = xg.y, g2 = xg.z, g3 = xg.w;
        #pragma unroll 4
        for (int k = 0; k < 256; ++k) {
            float h = hs[k];
            float4 w = *(const float4*)(whhT + (size_t)k*1024 + (tid << 2));
            g0 += h*w.x; g1 += h*w.y; g2 += h*w.z; g3 += h*w.w;
        }
        gl[4*tid]   = g0;
        gl[4*tid+1] = g1;
        gl[4*tid+2] = g2;
        gl[4*tid+3] = g3;
        __syncthreads();
        float gi = gl[tid], gf = gl[256+tid], gg = gl[512+tid], go = gl[768+tid];
        float cn = sigmoidf_(gf)*c + sigmoidf_(gi)*tanhf(gg);
        float hn = sigmoidf_(go)*tanhf(cn);
        c = cn;
        hs[tid] = hn;
        hcat[((size_t)b*31 + t)*512 + (size_t)d*256 + tid] = hn;
        __syncthreads();
    }
}

extern "C" void kernel_launch(void* const* d_in, const int* in_sizes, int n_in,
                              void* d_out, int out_size, void* d_ws, size_t ws_size,
                              hipStream_t stream)
{
    const float* x    = (const float*)d_in[0];
    const float* fW   = (const float*)d_in[1];
    const float* fB   = (const float*)d_in[2];
    const float* cbw1 = (const float*)d_in[3];
    const float* cbg  = (const float*)d_in[4];
    const float* cbb  = (const float*)d_in[5];
    const float* cbw2 = (const float*)d_in[6];
    const float* r1pg = (const float*)d_in[7];
    const float* r1pb = (const float*)d_in[8];
    const float* r1wA = (const float*)d_in[9];
    const float* r1g  = (const float*)d_in[10];
    const float* r1b  = (const float*)d_in[11];
    const float* r1wB = (const float*)d_in[12];
    const float* r1s  = (const float*)d_in[13];
    const float* r2pg = (const float*)d_in[14];
    const float* r2pb = (const float*)d_in[15];
    const float* r2wA = (const float*)d_in[16];
    const float* r2g  = (const float*)d_in[17];
    const float* r2b  = (const float*)d_in[18];
    const float* r2wB = (const float*)d_in[19];
    const float* r2s  = (const float*)d_in[20];
    const float* r3pg = (const float*)d_in[21];
    const float* r3pb = (const float*)d_in[22];
    const float* r3wA = (const float*)d_in[23];
    const float* r3g  = (const float*)d_in[24];
    const float* r3b  = (const float*)d_in[25];
    const float* r3wB = (const float*)d_in[26];
    const float* r3s  = (const float*)d_in[27];
    const float* pbg  = (const float*)d_in[28];
    const float* pbb  = (const float*)d_in[29];
    const float* wih_f = (const float*)d_in[30];
    const float* whh_f = (const float*)d_in[31];
    const float* bih_f = (const float*)d_in[32];
    const float* bhh_f = (const float*)d_in[33];
    const float* wih_b = (const float*)d_in[34];
    const float* whh_b = (const float*)d_in[35];
    const float* bih_b = (const float*)d_in[36];
    const float* bhh_b = (const float*)d_in[37];
    const float* clsw  = (const float*)d_in[38];
    const float* clsb  = (const float*)d_in[39];
    float* out = (float*)d_out;
    float* ws  = (float*)d_ws;

    // per-image chunk buffer sizes (floats)
    const size_t SZ_A1 = (size_t)64*31*513;   // 1,017,792
    const size_t SZ_C1 = (size_t)64*31*128;   //   253,952
    const size_t SZ_A2 = (size_t)128*31*128;  //   507,904
    const size_t SZ_C2 = (size_t)128*31*32;   //   126,976
    const size_t SZ_A3 = (size_t)192*31*32;   //   190,464
    const size_t SZ_C3 = (size_t)192*31*8;    //    47,616
    const size_t SZ_A4 = (size_t)256*31*8;    //    63,488
    const size_t PERIMG = SZ_A1+SZ_C1+SZ_A2+SZ_C2+SZ_A3+SZ_C3+SZ_A4;  // 2,208,192
    const size_t FIXED  = 508896 + 508896                // P, XM
                        + 507904 + 507904 + 262144       // P4, FE, WT
                        + 1015808 + 507904;              // XP, HC

    int NC = 0;
    const int cands[4] = {8,4,2,1};
    for (int i = 0; i < 4; ++i) {
        if ((FIXED + (size_t)cands[i]*PERIMG)*sizeof(float) <= ws_size) { NC = cands[i]; break; }
    }
    if (!NC) return;  // workspace too small even for NC=1 (~24 MB)

    float* P   = ws;
    float* XM  = P   + 508896;
    float* A1  = XM  + 508896;
    float* C1  = A1  + (size_t)NC*SZ_A1;
    float* A2  = C1  + (size_t)NC*SZ_C1;
    float* C2  = A2  + (size_t)NC*SZ_A2;
    float* A3  = C2  + (size_t)NC*SZ_C2;
    float* C3  = A3  + (size_t)NC*SZ_A3;
    float* A4  = C3  + (size_t)NC*SZ_C3;
    float* P4  = A4  + (size_t)NC*SZ_A4;
    float* FE  = P4  + 507904;
    float* WT  = FE  + 507904;
    float* XP  = WT  + 262144;
    float* HC  = XP  + 1015808;

    // frontend mask
    mask_partial_kernel<<<dim3(63, 32), 256, 0, stream>>>(fW, fB, P);
    mask_finalize_apply<<<63, 256, 0, stream>>>(P, x, XM);

    auto cdiv = [](int a, int b){ return (a + b - 1) / b; };

    for (int c0 = 0; c0 < 32; c0 += NC) {
        const float* xmc = XM + (size_t)c0*15903;
        // conv1: 1->64, W=513, bn(cbg,cbb)+lrelu
        conv3x3_kernel<<<dim3(cdiv(31*257,256), 16, NC), 256, 0, stream>>>(
            xmc, cbw1, A1, 1, 64, 31, 513, cbg, cbb, 1);
        // conv2 + bn(r1pg,r1pb)+lrelu+mp4: 64->64, W 513->128
        conv3x3_scpool_kernel<<<dim3(cdiv(31*128,256), 16, NC), 256, 0, stream>>>(
            A1, cbw2, nullptr, nullptr, C1, 64, 0, 64, 31, 513, 128, r1pg, r1pb);
        // r1 convA: 64->128, W=128, bn(r1g,r1b)+lrelu
        conv3x3_kernel<<<dim3(cdiv(31*64,256), 32, NC), 256, 0, stream>>>(
            C1, r1wA, A2, 64, 128, 31, 128, r1g, r1b, 1);
        // r1 convB + sc + bn(r2pg,r2pb)+lrelu+mp4: 128ch, W 128->32
        conv3x3_scpool_kernel<<<dim3(cdiv(31*32,256), 32, NC), 256, 0, stream>>>(
            A2, r1wB, C1, r1s, C2, 128, 64, 128, 31, 128, 32, r2pg, r2pb);
        // r2 convA: 128->192, W=32
        conv3x3_kernel<<<dim3(cdiv(31*16,256), 48, NC), 256, 0, stream>>>(
            C2, r2wA, A3, 128, 192, 31, 32, r2g, r2b, 1);
        // r2 convB + sc + bn(r3pg,r3pb)+lrelu+mp4: 192ch, W 32->8
        conv3x3_scpool_kernel<<<dim3(cdiv(31*8,256), 48, NC), 256, 0, stream>>>(
            A3, r2wB, C2, r2s, C3, 192, 128, 192, 31, 32, 8, r3pg, r3pb);
        // r3 convA: 192->256, W=8
        conv3x3_kernel<<<dim3(cdiv(31*4,256), 64, NC), 256, 0, stream>>>(
            C3, r3wA, A4, 192, 256, 31, 8, r3g, r3b, 1);
        // r3 convB + sc + bn(pbg,pbb)+lrelu+mp4: 256ch, W 8->2 -> P4 (full-batch offsets)
        conv3x3_scpool_kernel<<<dim3(cdiv(31*2,256), 64, NC), 256, 0, stream>>>(
            A4, r3wB, C3, r3s, P4 + (size_t)c0*15872, 256, 192, 256, 31, 8, 2, pbg, pbb);
    }

    // feats (32,31,512)
    feats_kernel<<<1984, 256, 0, stream>>>(P4, FE);

    // LSTM forward
    transpose_whh_kernel<<<1024, 256, 0, stream>>>(whh_f, WT);
    gemm_bias_kernel<<<dim3(31, 16), 256, 0, stream>>>(FE, wih_f, bih_f, bhh_f, XP, 992, 1024, 512);
    lstm_scan_kernel<<<32, 256, 0, stream>>>(XP, WT, HC, 0);

    // LSTM backward (reuse WT, XP)
    transpose_whh_kernel<<<1024, 256, 0, stream>>>(whh_b, WT);
    gemm_bias_kernel<<<dim3(31, 16), 256, 0, stream>>>(FE, wih_b, bih_b, bhh_b, XP, 992, 1024, 512);
    lstm_scan_kernel<<<32, 256, 0, stream>>>(XP, WT, HC, 1);

    // classifier -> d_out (32,31,722)
    gemm_bias_kernel<<<dim3(31, 12), 256, 0, stream>>>(HC, clsw, clsb, nullptr, out, 992, 722, 512);
}

// Round 3
// 2734.835 us; speedup vs baseline: 3.4553x; 3.4553x over previous
//
#include <hip/hip_runtime.h>
#include <hip/hip_bf16.h>
#include <math.h>

#define RSQ 0.99999500003749969f   // 1/sqrt(1+1e-5)
#define SLOPE 0.01f

typedef __attribute__((ext_vector_type(8))) short short8;
typedef __attribute__((ext_vector_type(4))) float f32x4;

__device__ __forceinline__ float sigmoidf_(float x){ return 1.0f/(1.0f+expf(-x)); }

__device__ __forceinline__ unsigned short f2bf(float f){
    unsigned u = __float_as_uint(f);
    u += 0x7fff + ((u >> 16) & 1);      // RNE
    return (unsigned short)(u >> 16);
}
__device__ __forceinline__ float bf2f(unsigned short s){
    return __uint_as_float(((unsigned)s) << 16);
}

// ---------------- mask: prod_k cos(fW*rng + fB) ----------------
__global__ void mask_partial_kernel(const float* __restrict__ fW, const float* __restrict__ fB,
                                    float* __restrict__ partial)
{
    int p = blockIdx.x*256 + threadIdx.x;   // 0..15902
    if (p >= 15903) return;
    int w = p % 513;
    float r = (float)(w + 1);
    int k0 = blockIdx.y * 32;
    float prod = 1.0f;
    for (int k = k0; k < k0 + 32; ++k) {
        float a = fW[(size_t)k*15903 + p] * r + fB[(size_t)k*15903 + p];
        prod *= cosf(a);
    }
    partial[blockIdx.y*15903 + p] = prod;
}

__global__ void mask_finalize_apply(const float* __restrict__ partial, const float* __restrict__ x,
                                    float* __restrict__ xm)
{
    int p = blockIdx.x*256 + threadIdx.x;
    if (p >= 15903) return;
    float m = 1.0f;
    #pragma unroll
    for (int c = 0; c < 32; ++c) m *= partial[c*15903 + p];
    for (int n = 0; n < 32; ++n)
        xm[(size_t)n*15903 + p] = x[(size_t)n*15903 + p] * m;
}

// ---------------- weight transforms ----------------
// OIHW fp32 -> [tap][co][ci] bf16
__global__ void wtrans9_kernel(const float* __restrict__ w, unsigned short* __restrict__ o,
                               int Cout, int Cin)
{
    int idx = blockIdx.x*256 + threadIdx.x;
    int cc = Cout*Cin;
    if (idx >= 9*cc) return;
    int tap = idx / cc;
    int r = idx - tap*cc;
    int co = r / Cin, ci = r - co*Cin;
    int kh = tap/3, kw = tap - kh*3;
    o[idx] = f2bf(w[((size_t)(co*Cin + ci)*3 + kh)*3 + kw]);
}
__global__ void wtrans1_kernel(const float* __restrict__ w, unsigned short* __restrict__ o, int total)
{
    int idx = blockIdx.x*256 + threadIdx.x;
    if (idx < total) o[idx] = f2bf(w[idx]);
}

// ---------------- conv1: Cin=1 direct, fp32 in -> bf16 NHWC out ----------------
__launch_bounds__(256)
__global__ void conv1_kernel(const float* __restrict__ xm, const float* __restrict__ w1,
                             const float* __restrict__ g, const float* __restrict__ b,
                             unsigned short* __restrict__ O)
{
    __shared__ float wl[576];
    __shared__ float sg[64], sb[64];
    int tid = threadIdx.x;
    if (tid < 64) { sg[tid] = g[tid]*RSQ; sb[tid] = b[tid]; }
    for (int i = tid; i < 576; i += 256) wl[i] = w1[i];
    __syncthreads();
    int px = blockIdx.x*256 + tid;
    int n = blockIdx.z;
    if (px >= 15903) return;
    int h = px / 513, w = px - h*513;
    const float* xp = xm + (size_t)n*15903;
    float v[9];
    #pragma unroll
    for (int dh = 0; dh < 3; ++dh)
      #pragma unroll
      for (int dw = 0; dw < 3; ++dw) {
        int hh = h+dh-1, ww = w+dw-1;
        bool ok = ((unsigned)hh < 31u) && ((unsigned)ww < 513u);
        v[dh*3+dw] = ok ? xp[hh*513 + ww] : 0.f;
      }
    unsigned short* op = O + ((size_t)n*15903 + px)*64;
    #pragma unroll
    for (int c8 = 0; c8 < 8; ++c8) {
        unsigned tmp[8];
        #pragma unroll
        for (int j = 0; j < 8; ++j) {
            int co = c8*8 + j;
            const float* wr = &wl[co*9];
            float a = 0.f;
            #pragma unroll
            for (int t2 = 0; t2 < 9; ++t2) a += wr[t2]*v[t2];
            a = a*sg[co] + sb[co];
            a = (a >= 0.f) ? a : SLOPE*a;
            tmp[j] = f2bf(a);
        }
        uint4 pk;
        pk.x = tmp[0] | (tmp[1]<<16);
        pk.y = tmp[2] | (tmp[3]<<16);
        pk.z = tmp[4] | (tmp[5]<<16);
        pk.w = tmp[6] | (tmp[7]<<16);
        *(uint4*)(op + c8*8) = pk;
    }
}

// ---------------- implicit-GEMM 3x3 conv (+fused 1x1 shortcut) via MFMA ----------------
// X: NHWC bf16 [n][H][W][Cin]; W9: [9][Cout][Cin] bf16; Xs/Ws: optional 1x1 path
// O: NHWC bf16 [n][H][W][Cout], epilogue bn(g,b)+lrelu.
// grid: (cdiv(H*W,64), Cout/64, NC); 256 thr = 4 waves; wave -> 16 co, 64 px (4 mfma tiles)
__launch_bounds__(256)
__global__ void conv_mfma_kernel(const unsigned short* __restrict__ X,
                                 const unsigned short* __restrict__ W9,
                                 const unsigned short* __restrict__ Xs,
                                 const unsigned short* __restrict__ Ws,
                                 unsigned short* __restrict__ O,
                                 int H, int W, int Cin, int Cs, int Cout,
                                 const float* __restrict__ g, const float* __restrict__ b)
{
    const int HW = H * W;
    const int lane = threadIdx.x & 63;
    const int wave = threadIdx.x >> 6;
    const int co64 = blockIdx.y * 64 + wave * 16;
    const int n = blockIdx.z;
    const int px0 = blockIdx.x * 64;
    const int l15 = lane & 15;
    const int kl = (lane >> 4) * 8;
    const short8 zf = {0,0,0,0,0,0,0,0};

    int hh_[4], ww_[4]; bool pv[4];
    #pragma unroll
    for (int t = 0; t < 4; ++t) {
        int px = px0 + t*16 + l15;
        pv[t] = px < HW;
        int pc = pv[t] ? px : 0;
        hh_[t] = pc / W;
        ww_[t] = pc - hh_[t]*W;
    }

    const unsigned short* Xn = X + (size_t)n * HW * Cin;
    f32x4 acc0 = {0,0,0,0}, acc1 = {0,0,0,0}, acc2 = {0,0,0,0}, acc3 = {0,0,0,0};

    for (int tap = 0; tap < 9; ++tap) {
        int dh = tap/3 - 1, dw = tap - (tap/3)*3 - 1;
        const short8* ap = (const short8*)(W9 + ((size_t)tap*Cout + co64 + l15)*Cin + kl);
        const short8* bp[4]; bool v[4];
        #pragma unroll
        for (int t = 0; t < 4; ++t) {
            int hh = hh_[t] + dh, ww = ww_[t] + dw;
            v[t] = pv[t] && ((unsigned)hh < (unsigned)H) && ((unsigned)ww < (unsigned)W);
            int p2 = v[t] ? (hh*W + ww) : 0;
            bp[t] = (const short8*)(Xn + (size_t)p2*Cin + kl);
        }
        for (int k0 = 0; k0 < Cin; k0 += 32) {
            int ko = k0 >> 3;
            short8 a  = ap[ko];
            short8 b0 = v[0] ? bp[0][ko] : zf;
            short8 b1 = v[1] ? bp[1][ko] : zf;
            short8 b2 = v[2] ? bp[2][ko] : zf;
            short8 b3 = v[3] ? bp[3][ko] : zf;
            acc0 = __builtin_amdgcn_mfma_f32_16x16x32_bf16(a, b0, acc0, 0, 0, 0);
            acc1 = __builtin_amdgcn_mfma_f32_16x16x32_bf16(a, b1, acc1, 0, 0, 0);
            acc2 = __builtin_amdgcn_mfma_f32_16x16x32_bf16(a, b2, acc2, 0, 0, 0);
            acc3 = __builtin_amdgcn_mfma_f32_16x16x32_bf16(a, b3, acc3, 0, 0, 0);
        }
    }

    if (Ws) {   // fused 1x1 shortcut on Xs (same H,W)
        const unsigned short* X2n = Xs + (size_t)n * HW * Cs;
        const short8* ap = (const short8*)(Ws + ((size_t)(co64 + l15))*Cs + kl);
        const short8* bp[4];
        #pragma unroll
        for (int t = 0; t < 4; ++t) {
            int p2 = pv[t] ? (hh_[t]*W + ww_[t]) : 0;
            bp[t] = (const short8*)(X2n + (size_t)p2*Cs + kl);
        }
        for (int k0 = 0; k0 < Cs; k0 += 32) {
            int ko = k0 >> 3;
            short8 a  = ap[ko];
            short8 b0 = pv[0] ? bp[0][ko] : zf;
            short8 b1 = pv[1] ? bp[1][ko] : zf;
            short8 b2 = pv[2] ? bp[2][ko] : zf;
            short8 b3 = pv[3] ? bp[3][ko] : zf;
            acc0 = __builtin_amdgcn_mfma_f32_16x16x32_bf16(a, b0, acc0, 0, 0, 0);
            acc1 = __builtin_amdgcn_mfma_f32_16x16x32_bf16(a, b1, acc1, 0, 0, 0);
            acc2 = __builtin_amdgcn_mfma_f32_16x16x32_bf16(a, b2, acc2, 0, 0, 0);
            acc3 = __builtin_amdgcn_mfma_f32_16x16x32_bf16(a, b3, acc3, 0, 0, 0);
        }
    }

    // epilogue: bn + lrelu -> bf16, 4 consecutive co per lane (8B store)
    int cb = co64 + (lane >> 4)*4;
    float s0 = g[cb+0]*RSQ, s1 = g[cb+1]*RSQ, s2 = g[cb+2]*RSQ, s3 = g[cb+3]*RSQ;
    float o0 = b[cb+0], o1 = b[cb+1], o2 = b[cb+2], o3 = b[cb+3];

#define EPI(ACC, T) do { \
    if (pv[T]) { \
        int px = px0 + (T)*16 + l15; \
        float v0 = ACC[0]*s0 + o0; v0 = (v0 >= 0.f) ? v0 : SLOPE*v0; \
        float v1 = ACC[1]*s1 + o1; v1 = (v1 >= 0.f) ? v1 : SLOPE*v1; \
        float v2 = ACC[2]*s2 + o2; v2 = (v2 >= 0.f) ? v2 : SLOPE*v2; \
        float v3 = ACC[3]*s3 + o3; v3 = (v3 >= 0.f) ? v3 : SLOPE*v3; \
        uint2 pk; \
        pk.x = (unsigned)f2bf(v0) | ((unsigned)f2bf(v1) << 16); \
        pk.y = (unsigned)f2bf(v2) | ((unsigned)f2bf(v3) << 16); \
        *(uint2*)(O + ((size_t)n*HW + px)*Cout + cb) = pk; \
    } \
} while(0)
    EPI(acc0, 0); EPI(acc1, 1); EPI(acc2, 2); EPI(acc3, 3);
#undef EPI
}

// ---------------- maxpool(1,4) VALID on NHWC bf16 ----------------
__global__ void pool_nhwc_kernel(const unsigned short* __restrict__ in,
                                 unsigned short* __restrict__ out,
                                 int W, int Wout, int C, int total8)
{
    int idx = blockIdx.x*256 + threadIdx.x;
    if (idx >= total8) return;
    int c8 = idx % (C >> 3);
    int r = idx / (C >> 3);
    int w = r % Wout;
    int nh = r / Wout;                  // n*H + h
    const unsigned short* ip = in + (((size_t)nh*W) + (size_t)w*4)*C + c8*8;
    float m0=-1e30f,m1=-1e30f,m2=-1e30f,m3=-1e30f,m4=-1e30f,m5=-1e30f,m6=-1e30f,m7=-1e30f;
    #pragma unroll
    for (int i = 0; i < 4; ++i) {
        uint4 u = *(const uint4*)(ip + (size_t)i*C);
        m0 = fmaxf(m0, bf2f((unsigned short)(u.x & 0xffff)));
        m1 = fmaxf(m1, bf2f((unsigned short)(u.x >> 16)));
        m2 = fmaxf(m2, bf2f((unsigned short)(u.y & 0xffff)));
        m3 = fmaxf(m3, bf2f((unsigned short)(u.y >> 16)));
        m4 = fmaxf(m4, bf2f((unsigned short)(u.z & 0xffff)));
        m5 = fmaxf(m5, bf2f((unsigned short)(u.z >> 16)));
        m6 = fmaxf(m6, bf2f((unsigned short)(u.w & 0xffff)));
        m7 = fmaxf(m7, bf2f((unsigned short)(u.w >> 16)));
    }
    uint4 ov;
    ov.x = (unsigned)f2bf(m0) | ((unsigned)f2bf(m1) << 16);
    ov.y = (unsigned)f2bf(m2) | ((unsigned)f2bf(m3) << 16);
    ov.z = (unsigned)f2bf(m4) | ((unsigned)f2bf(m5) << 16);
    ov.w = (unsigned)f2bf(m6) | ((unsigned)f2bf(m7) << 16);
    *(uint4*)(out + (size_t)idx*8) = ov;
}

// ---------------- feats: [n][31][2][256] bf16 NHWC -> [n][31][512] fp32 (c*2+w) ----------------
__global__ void feats_kernel(const unsigned short* __restrict__ p4, float* __restrict__ fe)
{
    int idx = blockIdx.x*256 + threadIdx.x;   // 507904
    int cw = idx & 511;
    int nh = idx >> 9;
    int c = cw >> 1, w = cw & 1;
    fe[idx] = bf2f(p4[((size_t)nh*2 + w)*256 + c]);
}

// ---------------- whh (1024,256) -> whhT (256,1024) ----------------
__global__ void transpose_whh_kernel(const float* __restrict__ whh, float* __restrict__ whhT)
{
    int idx = blockIdx.x*256 + threadIdx.x;  // 262144 exact
    int j = idx >> 8, k = idx & 255;
    whhT[(size_t)k*1024 + j] = whh[idx];
}

// ---------------- tiled SGEMM: C[M,N] = A[M,K] @ B[N,K]^T + bias(+bias2) ----------------
#define GM 32
#define GN 64
#define GK 32
__launch_bounds__(256)
__global__ void gemm_bias_kernel(const float* __restrict__ A, const float* __restrict__ B,
                                 const float* __restrict__ bias, const float* __restrict__ bias2,
                                 float* __restrict__ C, int M, int N, int K)
{
    __shared__ float As[GM][GK+1];
    __shared__ float Bs[GN][GK+1];
    int m0 = blockIdx.x*GM, n0 = blockIdx.y*GN;
    int tid = threadIdx.x;
    int mi = tid >> 4;
    int ni = (tid & 15) * 4;
    float acc[2][4] = {};

    for (int k0 = 0; k0 < K; k0 += GK) {
        for (int i = tid; i < GM*GK; i += 256) {
            int r = i >> 5, c = i & 31;
            int m = m0 + r;
            As[r][c] = (m < M) ? A[(size_t)m*K + k0 + c] : 0.f;
        }
        for (int i = tid; i < GN*GK; i += 256) {
            int r = i >> 5, c = i & 31;
            int n = n0 + r;
            Bs[r][c] = (n < N) ? B[(size_t)n*K + k0 + c] : 0.f;
        }
        __syncthreads();
        #pragma unroll
        for (int kk = 0; kk < GK; ++kk) {
            float a0 = As[mi][kk], a1 = As[mi+16][kk];
            float b0 = Bs[ni][kk], b1 = Bs[ni+1][kk], b2 = Bs[ni+2][kk], b3 = Bs[ni+3][kk];
            acc[0][0] += a0*b0; acc[0][1] += a0*b1; acc[0][2] += a0*b2; acc[0][3] += a0*b3;
            acc[1][0] += a1*b0; acc[1][1] += a1*b1; acc[1][2] += a1*b2; acc[1][3] += a1*b3;
        }
        __syncthreads();
    }
    #pragma unroll
    for (int r = 0; r < 2; ++r) {
        int m = m0 + mi + r*16;
        if (m >= M) continue;
        #pragma unroll
        for (int q = 0; q < 4; ++q) {
            int n = n0 + ni + q;
            if (n >= N) continue;
            float v = acc[r][q];
            if (bias)  v += bias[n];
            if (bias2) v += bias2[n];
            C[(size_t)m*N + n] = v;
        }
    }
}

// ---------------- LSTM scan (one direction) ----------------
__launch_bounds__(256)
__global__ void lstm_scan_kernel(const float* __restrict__ xp, const float* __restrict__ whhT,
                                 float* __restrict__ hcat, int d)
{
    int b = blockIdx.x;
    int tid = threadIdx.x;

    __shared__ float hs[256];
    __shared__ float gl[1024];
    hs[tid] = 0.f;
    float c = 0.f;
    __syncthreads();

    for (int step = 0; step < 31; ++step) {
        int t = d ? (30 - step) : step;
        const float* x = xp + ((size_t)b*31 + t)*1024;
        float4 xg = *(const float4*)(x + (tid << 2));
        float g0 = xg.x, g1 = xg.y, g2 = xg.z, g3 = xg.w;
        #pragma unroll 4
        for (int k = 0; k < 256; ++k) {
            float h = hs[k];
            float4 w = *(const float4*)(whhT + (size_t)k*1024 + (tid << 2));
            g0 += h*w.x; g1 += h*w.y; g2 += h*w.z; g3 += h*w.w;
        }
        gl[4*tid]   = g0;
        gl[4*tid+1] = g1;
        gl[4*tid+2] = g2;
        gl[4*tid+3] = g3;
        __syncthreads();
        float gi = gl[tid], gf = gl[256+tid], gg = gl[512+tid], go = gl[768+tid];
        float cn = sigmoidf_(gf)*c + sigmoidf_(gi)*tanhf(gg);
        float hn = sigmoidf_(go)*tanhf(cn);
        c = cn;
        hs[tid] = hn;
        hcat[((size_t)b*31 + t)*512 + (size_t)d*256 + tid] = hn;
        __syncthreads();
    }
}

extern "C" void kernel_launch(void* const* d_in, const int* in_sizes, int n_in,
                              void* d_out, int out_size, void* d_ws, size_t ws_size,
                              hipStream_t stream)
{
    const float* x    = (const float*)d_in[0];
    const float* fW   = (const float*)d_in[1];
    const float* fB   = (const float*)d_in[2];
    const float* cbw1 = (const float*)d_in[3];
    const float* cbg  = (const float*)d_in[4];
    const float* cbb  = (const float*)d_in[5];
    const float* cbw2 = (const float*)d_in[6];
    const float* r1pg = (const float*)d_in[7];
    const float* r1pb = (const float*)d_in[8];
    const float* r1wA = (const float*)d_in[9];
    const float* r1g  = (const float*)d_in[10];
    const float* r1b  = (const float*)d_in[11];
    const float* r1wB = (const float*)d_in[12];
    const float* r1s  = (const float*)d_in[13];
    const float* r2pg = (const float*)d_in[14];
    const float* r2pb = (const float*)d_in[15];
    const float* r2wA = (const float*)d_in[16];
    const float* r2g  = (const float*)d_in[17];
    const float* r2b  = (const float*)d_in[18];
    const float* r2wB = (const float*)d_in[19];
    const float* r2s  = (const float*)d_in[20];
    const float* r3pg = (const float*)d_in[21];
    const float* r3pb = (const float*)d_in[22];
    const float* r3wA = (const float*)d_in[23];
    const float* r3g  = (const float*)d_in[24];
    const float* r3b  = (const float*)d_in[25];
    const float* r3wB = (const float*)d_in[26];
    const float* r3s  = (const float*)d_in[27];
    const float* pbg  = (const float*)d_in[28];
    const float* pbb  = (const float*)d_in[29];
    const float* wih_f = (const float*)d_in[30];
    const float* whh_f = (const float*)d_in[31];
    const float* bih_f = (const float*)d_in[32];
    const float* bhh_f = (const float*)d_in[33];
    const float* wih_b = (const float*)d_in[34];
    const float* whh_b = (const float*)d_in[35];
    const float* bih_b = (const float*)d_in[36];
    const float* bhh_b = (const float*)d_in[37];
    const float* clsw  = (const float*)d_in[38];
    const float* clsb  = (const float*)d_in[39];
    float* out = (float*)d_out;
    float* ws  = (float*)d_ws;

    // ---- workspace sizing (floats) ----
    const size_t FIXEDF = 962560      // transformed weights (1,925,120 ushort)
                        + 508896      // P
                        + 508896      // XM
                        + 253952      // XP4 (bf16)
                        + 507904      // FE
                        + 262144      // WT
                        + 1015808     // XPj
                        + 507904;     // HC
    const size_t PCF = 508896*2 + 126976 + 63488 + 23808;  // per-image chunk floats
    int NC = 0;
    const int cands[4] = {8,4,2,1};
    for (int i = 0; i < 4; ++i) {
        if ((FIXEDF + (size_t)cands[i]*PCF)*sizeof(float) <= ws_size) { NC = cands[i]; break; }
    }
    if (!NC) return;

    float* p = ws;
    unsigned short* WTR = (unsigned short*)p; p += 962560;
    float* P   = p; p += 508896;
    float* XM  = p; p += 508896;
    unsigned short* XP4 = (unsigned short*)p; p += 253952;
    float* FE  = p; p += 507904;
    float* WT  = p; p += 262144;
    float* XPj = p; p += 1015808;
    float* HC  = p; p += 507904;
    unsigned short* REG1 = (unsigned short*)p; p += (size_t)NC*508896;
    unsigned short* REG2 = (unsigned short*)p; p += (size_t)NC*508896;
    unsigned short* XP1c = (unsigned short*)p; p += (size_t)NC*126976;
    unsigned short* XP2c = (unsigned short*)p; p += (size_t)NC*63488;
    unsigned short* XP3c = (unsigned short*)p; p += (size_t)NC*23808;

    // transformed-weight sub-offsets (ushorts)
    unsigned short* w2T  = WTR + 0;
    unsigned short* r1AT = WTR + 36864;
    unsigned short* r1BT = WTR + 110592;
    unsigned short* r1ST = WTR + 258048;
    unsigned short* r2AT = WTR + 266240;
    unsigned short* r2BT = WTR + 487424;
    unsigned short* r2ST = WTR + 819200;
    unsigned short* r3AT = WTR + 843776;
    unsigned short* r3BT = WTR + 1286144;
    unsigned short* r3ST = WTR + 1875968;

    auto cdiv = [](int a, int b){ return (a + b - 1) / b; };

    // ---- weight transforms ----
    wtrans9_kernel<<<cdiv(9*64*64,256),   256, 0, stream>>>(cbw2, w2T, 64, 64);
    wtrans9_kernel<<<cdiv(9*128*64,256),  256, 0, stream>>>(r1wA, r1AT, 128, 64);
    wtrans9_kernel<<<cdiv(9*128*128,256), 256, 0, stream>>>(r1wB, r1BT, 128, 128);
    wtrans1_kernel<<<cdiv(128*64,256),    256, 0, stream>>>(r1s, r1ST, 128*64);
    wtrans9_kernel<<<cdiv(9*192*128,256), 256, 0, stream>>>(r2wA, r2AT, 192, 128);
    wtrans9_kernel<<<cdiv(9*192*192,256), 256, 0, stream>>>(r2wB, r2BT, 192, 192);
    wtrans1_kernel<<<cdiv(192*128,256),   256, 0, stream>>>(r2s, r2ST, 192*128);
    wtrans9_kernel<<<cdiv(9*256*192,256), 256, 0, stream>>>(r3wA, r3AT, 256, 192);
    wtrans9_kernel<<<cdiv(9*256*256,256), 256, 0, stream>>>(r3wB, r3BT, 256, 256);
    wtrans1_kernel<<<cdiv(256*192,256),   256, 0, stream>>>(r3s, r3ST, 256*192);

    // ---- frontend mask ----
    mask_partial_kernel<<<dim3(63, 32), 256, 0, stream>>>(fW, fB, P);
    mask_finalize_apply<<<63, 256, 0, stream>>>(P, x, XM);

    // ---- conv stack, chunked over batch ----
    for (int c0 = 0; c0 < 32; c0 += NC) {
        const float* xmc = XM + (size_t)c0*15903;
        // conv1: 1->64 direct, bn(cbg,cbb)+lrelu, out NHWC bf16 [NC][31][513][64] in REG1
        conv1_kernel<<<dim3(63, 1, NC), 256, 0, stream>>>(xmc, cbw1, cbg, cbb, REG1);
        // conv2 (mfma): 64->64, epi bn(r1pg,r1pb)+lrelu -> REG2
        conv_mfma_kernel<<<dim3(cdiv(15903,64), 1, NC), 256, 0, stream>>>(
            REG1, w2T, nullptr, nullptr, REG2, 31, 513, 64, 0, 64, r1pg, r1pb);
        // pool 513->128 -> XP1c
        pool_nhwc_kernel<<<cdiv(NC*31*128*8,256), 256, 0, stream>>>(REG2, XP1c, 513, 128, 64, NC*31*128*8);
        // r1A (mfma): 64->128, bn(r1g,r1b)+lrelu -> REG1
        conv_mfma_kernel<<<dim3(cdiv(31*128,64), 2, NC), 256, 0, stream>>>(
            XP1c, r1AT, nullptr, nullptr, REG1, 31, 128, 64, 0, 128, r1g, r1b);
        // r1B + shortcut (mfma): epi bn(r2pg,r2pb)+lrelu -> REG2
        conv_mfma_kernel<<<dim3(cdiv(31*128,64), 2, NC), 256, 0, stream>>>(
            REG1, r1BT, XP1c, r1ST, REG2, 31, 128, 128, 64, 128, r2pg, r2pb);
        // pool 128->32 -> XP2c
        pool_nhwc_kernel<<<cdiv(NC*31*32*16,256), 256, 0, stream>>>(REG2, XP2c, 128, 32, 128, NC*31*32*16);
        // r2A: 128->192, bn(r2g,r2b)+lrelu -> REG1
        conv_mfma_kernel<<<dim3(cdiv(31*32,64), 3, NC), 256, 0, stream>>>(
            XP2c, r2AT, nullptr, nullptr, REG1, 31, 32, 128, 0, 192, r2g, r2b);
        // r2B + shortcut: epi bn(r3pg,r3pb)+lrelu -> REG2
        conv_mfma_kernel<<<dim3(cdiv(31*32,64), 3, NC), 256, 0, stream>>>(
            REG1, r2BT, XP2c, r2ST, REG2, 31, 32, 192, 128, 192, r3pg, r3pb);
        // pool 32->8 -> XP3c
        pool_nhwc_kernel<<<cdiv(NC*31*8*24,256), 256, 0, stream>>>(REG2, XP3c, 32, 8, 192, NC*31*8*24);
        // r3A: 192->256, bn(r3g,r3b)+lrelu -> REG1
        conv_mfma_kernel<<<dim3(cdiv(31*8,64), 4, NC), 256, 0, stream>>>(
            XP3c, r3AT, nullptr, nullptr, REG1, 31, 8, 192, 0, 256, r3g, r3b);
        // r3B + shortcut: epi bn(pbg,pbb)+lrelu -> REG2
        conv_mfma_kernel<<<dim3(cdiv(31*8,64), 4, NC), 256, 0, stream>>>(
            REG1, r3BT, XP3c, r3ST, REG2, 31, 8, 256, 192, 256, pbg, pbb);
        // pool 8->2 -> XP4 slice (global batch offset)
        pool_nhwc_kernel<<<cdiv(NC*31*2*32,256), 256, 0, stream>>>(
            REG2, XP4 + (size_t)c0*15872, 8, 2, 256, NC*31*2*32);
    }

    // feats (32,31,512) fp32
    feats_kernel<<<1984, 256, 0, stream>>>(XP4, FE);

    // LSTM forward
    transpose_whh_kernel<<<1024, 256, 0, stream>>>(whh_f, WT);
    gemm_bias_kernel<<<dim3(31, 16), 256, 0, stream>>>(FE, wih_f, bih_f, bhh_f, XPj, 992, 1024, 512);
    lstm_scan_kernel<<<32, 256, 0, stream>>>(XPj, WT, HC, 0);

    // LSTM backward (reuse WT, XPj)
    transpose_whh_kernel<<<1024, 256, 0, stream>>>(whh_b, WT);
    gemm_bias_kernel<<<dim3(31, 16), 256, 0, stream>>>(FE, wih_b, bih_b, bhh_b, XPj, 992, 1024, 512);
    lstm_scan_kernel<<<32, 256, 0, stream>>>(XPj, WT, HC, 1);

    // classifier -> d_out (32,31,722)
    gemm_bias_kernel<<<dim3(31, 12), 256, 0, stream>>>(HC, clsw, clsb, nullptr, out, 992, 722, 512);
}